// Round 1
// baseline (92.148 us; speedup 1.0000x reference)
//
#include <hip/hip_runtime.h>

// out[b] = P @ X[b] @ P^T where P (7140x1024) is a 0/1 matrix with exactly one
// 1 per column => pure scatter: out[b][r(i)][r(j)] = X[b][i][j], zeros elsewhere.
// r(i) = lexicographic rank of the combination (line, 16+col, 32+ch) in C(36,3).

constexpr int D_IN        = 1024;
constexpr int D_OUT       = 7140;           // C(36,3)
constexpr int VEC_PER_ROW = D_OUT / 4;      // 1785 float4 per output row
constexpr int N_QUBITS    = 36;

__global__ __launch_bounds__(256) void sandwich_scatter_kernel(
    const float* __restrict__ in, float* __restrict__ out, int total_vec)
{
    // Inverse LUT: output row index -> input index, or -1 (zero row/col).
    __shared__ __align__(16) short inv[D_OUT];

    for (int t = threadIdx.x; t < D_OUT; t += blockDim.x) inv[t] = -1;
    __syncthreads();

    for (int t = threadIdx.x; t < D_IN; t += blockDim.x) {
        int ch   = t & 3;
        int col  = (t >> 2) & 15;
        int line = t >> 6;
        int a = line;           // in [0,16)
        int b = 16 + col;       // in [16,32)
        int c = 32 + ch;        // in [32,36)
        // lex rank of (a<b<c) among combinations of {0..35} choose 3
        int r = 0;
        for (int x = 0; x < a; ++x) r += (N_QUBITS - 1 - x) * (N_QUBITS - 2 - x) / 2;
        for (int y = a + 1; y < b; ++y) r += N_QUBITS - 1 - y;
        r += c - b - 1;
        inv[r] = (short)t;
    }
    __syncthreads();

    const int tid    = blockIdx.x * blockDim.x + threadIdx.x;
    const int stride = gridDim.x * blockDim.x;

    for (int idx = tid; idx < total_vec; idx += stride) {
        int pv  = idx % VEC_PER_ROW;        // which float4 within the row
        int row = idx / VEC_PER_ROW;        // b*D_OUT + o
        int o   = row % D_OUT;
        int b   = row / D_OUT;

        float4 v = make_float4(0.f, 0.f, 0.f, 0.f);
        int io = inv[o];                    // wave-uniform most of the time
        if (io >= 0) {
            const float* __restrict__ srow =
                in + (size_t)b * (D_IN * D_IN) + (size_t)io * D_IN;
            short4 iv = *reinterpret_cast<const short4*>(&inv[pv * 4]);
            if (iv.x >= 0) v.x = srow[iv.x];
            if (iv.y >= 0) v.y = srow[iv.y];
            if (iv.z >= 0) v.z = srow[iv.z];
            if (iv.w >= 0) v.w = srow[iv.w];
        }
        reinterpret_cast<float4*>(out)[idx] = v;
    }
}

extern "C" void kernel_launch(void* const* d_in, const int* in_sizes, int n_in,
                              void* d_out, int out_size, void* d_ws, size_t ws_size,
                              hipStream_t stream) {
    const float* in = (const float*)d_in[0];   // (2, 1024, 1024) f32
    float* out = (float*)d_out;                // (2, 7140, 7140) f32

    int total_vec = out_size / 4;              // 25,489,800 float4 slots
    dim3 grid(2048), block(256);
    hipLaunchKernelGGL(sandwich_scatter_kernel, grid, block, 0, stream,
                       in, out, total_vec);
}